// Round 8
// baseline (44.454 us; speedup 1.0000x reference)
//
#include <hip/hip_runtime.h>

#define EDGE_EPS 1e-8f

typedef float fvec4 __attribute__((ext_vector_type(4)));   // 16B-aligned vec4

struct V3 { float x, y, z; };
struct V4 { float x, y, z, w; };

__device__ __forceinline__ V3 v3(float a, float b, float c) { V3 r{a,b,c}; return r; }

__device__ __forceinline__ V3 addv(V3 a, V3 b) { return v3(a.x+b.x, a.y+b.y, a.z+b.z); }
__device__ __forceinline__ V3 subv(V3 a, V3 b) { return v3(a.x-b.x, a.y-b.y, a.z-b.z); }
__device__ __forceinline__ V3 muls(V3 a, float s) { return v3(a.x*s, a.y*s, a.z*s); }
__device__ __forceinline__ float dotv(V3 a, V3 b) { return a.x*b.x + a.y*b.y + a.z*b.z; }
__device__ __forceinline__ V3 crossv(V3 a, V3 b) {
    return v3(a.y*b.z - a.z*b.y,
              a.z*b.x - a.x*b.z,
              a.x*b.y - a.y*b.x);
}

__device__ __forceinline__ V4 qmul(V4 a, V4 b) {
    V3 v1 = v3(a.x, a.y, a.z), v2 = v3(b.x, b.y, b.z);
    V3 c = crossv(v1, v2);
    V4 r;
    r.x = a.w*b.x + b.w*a.x + c.x;
    r.y = a.w*b.y + b.w*a.y + c.y;
    r.z = a.w*b.z + b.w*a.z + c.z;
    r.w = a.w*b.w - dotv(v1, v2);
    return r;
}

__device__ __forceinline__ V3 qact(V4 q, V3 t) {
    V3 v = v3(q.x, q.y, q.z);
    V3 inner = crossv(v, t);
    inner.x += q.w * t.x; inner.y += q.w * t.y; inner.z += q.w * t.z;
    V3 o = crossv(v, inner);
    return v3(t.x + 2.0f*o.x, t.y + 2.0f*o.y, t.z + 2.0f*o.z);
}

__device__ __forceinline__ V3 qlog(V4 q) {
    float sgn = (q.w >= 0.0f) ? 1.0f : -1.0f;
    float x = q.x * sgn, y = q.y * sgn, z = q.z * sgn, w = q.w * sgn;
    float n = sqrtf(x*x + y*y + z*z);
    float theta = 2.0f * atan2f(n, w);
    float coef = (n < EDGE_EPS) ? 2.0f : theta / fmaxf(n, EDGE_EPS);
    return v3(coef*x, coef*y, coef*z);
}

__device__ __forceinline__ V4 qinvq(V4 q) { V4 r{-q.x,-q.y,-q.z,q.w}; return r; }

__device__ __forceinline__ V3 ld3(const float* __restrict__ p, int idx) {
    return v3(p[3*idx+0], p[3*idx+1], p[3*idx+2]);
}

struct EdgeIn {
    V4 Rk, Rk1, dRk, vRk;
    V3 tk, tk1, vk, vk1, bak, bak1, bgk, bgk1, dvk, dpk, vtk;
    float dtk;
};

__device__ __forceinline__ void load_edge(
    int k, const float* __restrict__ R0, const float* __restrict__ t0,
    const float4* __restrict__ rot, const float* __restrict__ trans,
    const float* __restrict__ vel, const float* __restrict__ ba,
    const float* __restrict__ bg, const float4* __restrict__ dRq,
    const float* __restrict__ dv, const float* __restrict__ dp,
    const float* __restrict__ dt, const float4* __restrict__ vRq,
    const float* __restrict__ vt, EdgeIn& e)
{
    if (k == 0) {
        e.Rk = V4{R0[0], R0[1], R0[2], R0[3]};
        e.tk = v3(t0[0], t0[1], t0[2]);
    } else {
        float4 r = rot[k-1];
        e.Rk = V4{r.x, r.y, r.z, r.w};
        e.tk = ld3(trans, k-1);
    }
    float4 r1 = rot[k];  e.Rk1 = V4{r1.x, r1.y, r1.z, r1.w};
    float4 dr = dRq[k];  e.dRk = V4{dr.x, dr.y, dr.z, dr.w};
    float4 vr = vRq[k];  e.vRk = V4{vr.x, vr.y, vr.z, vr.w};
    e.dtk  = dt[k];
    e.tk1  = ld3(trans, k);
    e.vk   = ld3(vel, k);
    e.vk1  = ld3(vel, k+1);
    e.bak  = ld3(ba, k);
    e.bak1 = ld3(ba, k+1);
    e.bgk  = ld3(bg, k);
    e.bgk1 = ld3(bg, k+1);
    e.dvk  = ld3(dv, k);
    e.dpk  = ld3(dp, k);
    e.vtk  = ld3(vt, k);
}

__device__ __forceinline__ void compute_edge(const EdgeIn& e, float res[27])
{
    V4 Rinv = qinvq(e.Rk);
    V4 relR = qmul(Rinv, e.Rk1);
    V3 dtrans = subv(e.tk1, e.tk);
    V3 rel_t_est = qact(Rinv, dtrans);

    V3 r_rot = addv(qlog(qmul(qinvq(e.dRk), relR)), muls(e.bgk, e.dtk));

    V3 r_cross = qact(Rinv, subv(dtrans, muls(e.vk, e.dtk)));
    r_cross = addv(subv(r_cross, e.dpk), muls(e.bak, 0.5f*e.dtk*e.dtk));

    V3 r_deltav = addv(subv(subv(e.vk1, e.vk), qact(e.Rk, e.dvk)), muls(e.bak, e.dtk));

    V3 r_vis_rot = qlog(qmul(qinvq(e.vRk), relR));
    V3 r_vis_t   = subv(rel_t_est, e.vtk);

    res[ 0] = r_vis_rot.x; res[ 1] = r_vis_rot.y; res[ 2] = r_vis_rot.z;
    res[ 3] = r_vis_t.x;   res[ 4] = r_vis_t.y;   res[ 5] = r_vis_t.z;
    res[ 6] = r_rot.x;     res[ 7] = r_rot.y;     res[ 8] = r_rot.z;
    res[ 9] = r_cross.x;   res[10] = r_cross.y;   res[11] = r_cross.z;
    res[12] = r_deltav.x;  res[13] = r_deltav.y;  res[14] = r_deltav.z;
    res[15] = e.bak1.x - e.bak.x; res[16] = e.bak1.y - e.bak.y; res[17] = e.bak1.z - e.bak.z;
    res[18] = e.bgk1.x - e.bgk.x; res[19] = e.bgk1.y - e.bgk.y; res[20] = e.bgk1.z - e.bgk.z;
    res[21] = e.bak.x;     res[22] = e.bak.y;     res[23] = e.bak.z;
    res[24] = e.bgk.x;     res[25] = e.bgk.y;     res[26] = e.bgk.z;
}

__global__ void __launch_bounds__(256)
swc_kernel(const float* __restrict__ R0, const float* __restrict__ t0,
           const float4* __restrict__ rot,  const float* __restrict__ trans,
           const float* __restrict__ vel,   const float* __restrict__ ba,
           const float* __restrict__ bg,    const float4* __restrict__ dRq,
           const float* __restrict__ dv,    const float* __restrict__ dp,
           const float* __restrict__ dt,    const float4* __restrict__ vRq,
           const float* __restrict__ vt,    float* __restrict__ out, int N)
{
    // 256-edge output transpose buffer, used twice (once per edge set).
    __shared__ __align__(16) float obuf[256 * 27];

    const int base = blockIdx.x * 512;        // 512 edges per block
    const int tid  = threadIdx.x;
    const int k0   = base + tid;              // edge set 0: [base, base+256)
    const int k1   = base + 256 + tid;        // edge set 1: [base+256, base+512)
    const bool a0 = (k0 < N);
    const bool a1 = (k1 < N);

    // ---- issue both edges' loads back-to-back (2x MLP), then compute ----
    EdgeIn e0, e1;
    if (a0) load_edge(k0, R0, t0, rot, trans, vel, ba, bg, dRq, dv, dp, dt, vRq, vt, e0);
    if (a1) load_edge(k1, R0, t0, rot, trans, vel, ba, bg, dRq, dv, dp, dt, vRq, vt, e1);

    float res0[27], res1[27];
    if (a0) compute_edge(e0, res0);
    if (a1) compute_edge(e1, res1);

    const int cnt = min(512, N - base);       // edges covered by this block

    // ---- phase A: edges [base, base+256) ----
    if (cnt >= 256) {
        if (a0) {
            #pragma unroll
            for (int r = 0; r < 27; ++r) obuf[tid * 27 + r] = res0[r];
        }
        __syncthreads();
        const fvec4* s4 = reinterpret_cast<const fvec4*>(obuf);
        fvec4* o4 = reinterpret_cast<fvec4*>(out + (size_t)base * 27);
        #pragma unroll
        for (int rep = 0; rep < 7; ++rep) {
            int j = tid + rep * 256;
            if (j < 1728) __builtin_nontemporal_store(s4[j], &o4[j]);
        }
        __syncthreads();
    } else {
        if (a0) {
            float* og = out + (size_t)k0 * 27;
            #pragma unroll
            for (int r = 0; r < 27; ++r) __builtin_nontemporal_store(res0[r], &og[r]);
        }
    }

    // ---- phase B: edges [base+256, base+512) ----
    if (cnt == 512) {
        #pragma unroll
        for (int r = 0; r < 27; ++r) obuf[tid * 27 + r] = res1[r];
        __syncthreads();
        const fvec4* s4 = reinterpret_cast<const fvec4*>(obuf);
        fvec4* o4 = reinterpret_cast<fvec4*>(out + (size_t)(base + 256) * 27);
        #pragma unroll
        for (int rep = 0; rep < 7; ++rep) {
            int j = tid + rep * 256;
            if (j < 1728) __builtin_nontemporal_store(s4[j], &o4[j]);
        }
    } else {
        if (a1) {
            float* og = out + (size_t)k1 * 27;
            #pragma unroll
            for (int r = 0; r < 27; ++r) __builtin_nontemporal_store(res1[r], &og[r]);
        }
    }
}

extern "C" void kernel_launch(void* const* d_in, const int* in_sizes, int n_in,
                              void* d_out, int out_size, void* d_ws, size_t ws_size,
                              hipStream_t stream) {
    const float*  R0    = (const float*)d_in[0];
    const float*  t0    = (const float*)d_in[1];
    const float4* rot   = (const float4*)d_in[2];
    const float*  trans = (const float*)d_in[3];
    const float*  vel   = (const float*)d_in[4];
    const float*  ba    = (const float*)d_in[5];
    const float*  bg    = (const float*)d_in[6];
    const float4* dRq   = (const float4*)d_in[7];
    const float*  dv    = (const float*)d_in[8];
    const float*  dp    = (const float*)d_in[9];
    const float*  dt    = (const float*)d_in[10];
    const float4* vRq   = (const float4*)d_in[11];
    const float*  vt    = (const float*)d_in[12];
    float* out = (float*)d_out;

    int N = in_sizes[2] / 4;   // rotations: (W-1, 4)
    int grid = (N + 511) / 512;
    swc_kernel<<<grid, 256, 0, stream>>>(R0, t0, rot, trans, vel, ba, bg,
                                         dRq, dv, dp, dt, vRq, vt, out, N);
}